// Round 2
// baseline (424.176 us; speedup 1.0000x reference)
//
#include <hip/hip_runtime.h>
#include <cstdint>

#define NEGF (-1e18f)

typedef __attribute__((ext_vector_type(8))) short short8;     // 8 bf16 (4 VGPRs) MFMA A/B frag
typedef __attribute__((ext_vector_type(4))) float f32x4;      // MFMA C/D frag
typedef __attribute__((ext_vector_type(4))) unsigned short us4;
typedef __attribute__((ext_vector_type(8))) unsigned short us8;

__device__ __forceinline__ unsigned short f2bf(float f) {
    unsigned int u = __float_as_uint(f);
    u += 0x7FFFu + ((u >> 16) & 1u);          // RNE
    return (unsigned short)(u >> 16);
}
__device__ __forceinline__ float bf2f(unsigned short h) {
    return __uint_as_float(((unsigned int)h) << 16);
}
__device__ __forceinline__ float gelu_erf(float x) {
    return 0.5f * x * (1.0f + erff(x * 0.70710678118654752f));
}
__device__ __forceinline__ void async_copy16(const void* g, void* l) {
    __builtin_amdgcn_global_load_lds(
        (const __attribute__((address_space(1))) unsigned int*)g,
        (__attribute__((address_space(3))) unsigned int*)l,
        16, 0, 0);
}

// ---------------- 1. weight transpose + bf16 convert: w[K=2048][N=1024] -> wT[N][K] bf16
__global__ __launch_bounds__(256) void wtrans_kernel(const float* __restrict__ w,
                                                     unsigned short* __restrict__ wT) {
    const int idx = blockIdx.x * 256 + threadIdx.x;   // 1024 blocks * 256
    const int n = idx & 1023;
    const int k0 = (idx >> 10) << 3;
    us8 o;
    #pragma unroll
    for (int j = 0; j < 8; ++j) o[j] = f2bf(w[(size_t)(k0 + j) * 1024 + n]);
    *(us8*)(wT + (size_t)n * 2048 + k0) = o;
}

// ---------------- 2. masked motion scores: (B*L) row-dots over D=2048
__global__ __launch_bounds__(256) void score_kernel(const float* __restrict__ clip_ft,
                                                    const int* __restrict__ lens,
                                                    const float* __restrict__ w,
                                                    const float* __restrict__ bsc,
                                                    float* __restrict__ scores) {
    const int r = blockIdx.x * 4 + (threadIdx.x >> 6);   // one wave per row
    const int lane = threadIdx.x & 63;
    const float* row = clip_ft + (size_t)r * 2048;
    float sum = 0.f;
    #pragma unroll
    for (int j = 0; j < 8; ++j) {
        const int k = (j * 64 + lane) * 4;
        f32x4 x = *(const f32x4*)(row + k);
        f32x4 ww = *(const f32x4*)(w + k);
        sum += x[0]*ww[0] + x[1]*ww[1] + x[2]*ww[2] + x[3]*ww[3];
    }
    #pragma unroll
    for (int off = 32; off; off >>= 1) sum += __shfl_xor(sum, off);
    if (lane == 0) {
        const int b = r >> 8, l = r & 255;
        float v = sum + bsc[0];
        if (l >= lens[b]) v = NEGF;
        scores[r] = v;
    }
}

// ---------------- 3. fused: app bf16 convert + window softmax + vid_clip bf16
// grid: B * 8 chunks of 32 windows; thread owns 8 d-columns; rolling 3-row register window
__global__ __launch_bounds__(256) void prep_kernel(const float* __restrict__ clip_ft,
                                                   const float* __restrict__ scores,
                                                   unsigned short* __restrict__ app,   // [B][256][2048]
                                                   unsigned short* __restrict__ vid) { // [B][254][2048]
    const int b = blockIdx.x >> 3;
    const int c = blockIdx.x & 7;
    const int t = threadIdx.x;
    const int d0 = t * 8;
    const int l0 = c * 32;
    const float* base = clip_ft + ((size_t)b * 256) * 2048 + d0;
    const float* sc = scores + b * 256;
    float x0[8], x1[8], cur[8];
    for (int i = 0; i < 34; ++i) {
        const int l = l0 + i;
        if (l < 256) {
            const f32x4* p = (const f32x4*)(base + (size_t)l * 2048);
            f32x4 u = p[0], v = p[1];
            #pragma unroll
            for (int j = 0; j < 4; ++j) { cur[j] = u[j]; cur[4 + j] = v[j]; }
            if (i < 32) {
                us8 o;
                #pragma unroll
                for (int j = 0; j < 8; ++j) o[j] = f2bf(cur[j]);
                *(us8*)(app + ((size_t)b * 256 + l) * 2048 + d0) = o;
            }
        }
        if (i >= 2) {
            const int lw = l - 2;
            if (lw < 254) {
                const float s0 = sc[lw], s1 = sc[lw + 1], s2 = sc[lw + 2];
                const float mx = fmaxf(s0, fmaxf(s1, s2));
                const float e0 = expf(s0 - mx), e1 = expf(s1 - mx), e2 = expf(s2 - mx);
                const float inv = 1.0f / (e0 + e1 + e2);
                const float a0 = e0 * inv, a1 = e1 * inv, a2 = e2 * inv;
                us8 o;
                #pragma unroll
                for (int j = 0; j < 8; ++j) o[j] = f2bf(a0 * x0[j] + a1 * x1[j] + a2 * cur[j]);
                *(us8*)(vid + ((size_t)b * 254 + lw) * 2048 + d0) = o;
            }
        }
        #pragma unroll
        for (int j = 0; j < 8; ++j) { x0[j] = x1[j]; x1[j] = cur[j]; }
    }
}

// ---------------- 4. bf16 MFMA GEMM, m97 structure: 128x128 tile, BK=32, gelu epilogue
// A [M][2048] bf16 row-major, Bt [1024][2048] bf16 (N-major), C [M][1024] bf16
__global__ __launch_bounds__(256, 2) void gemm_gelu_kernel(const unsigned short* __restrict__ A,
                                                           const unsigned short* __restrict__ Bt,
                                                           const float* __restrict__ bias,
                                                           unsigned short* __restrict__ C) {
    const int K = 2048;
    __shared__ __align__(16) unsigned short As[128 * 32];
    __shared__ __align__(16) unsigned short Bs[128 * 32];
    const int t = threadIdx.x;
    const int lane = t & 63;
    const int wave = t >> 6;
    const int wr = wave >> 1, wc = wave & 1;
    const int ncol = blockIdx.x & 7;          // 8 N-tiles; col fastest -> A panel L2 reuse
    const int nrow = blockIdx.x >> 3;
    const int rowBase = nrow * 128, colBase = ncol * 128;

    const unsigned short* gA = A + (size_t)(rowBase + (t >> 2)) * K + (t & 3) * 8;
    const unsigned short* gB = Bt + (size_t)(colBase + (t >> 2)) * K + (t & 3) * 8;
    unsigned short* ldsA = As + wave * 512;   // wave-uniform dst; HW adds lane*16B
    unsigned short* ldsB = Bs + wave * 512;

    f32x4 acc[4][4] = {};
    const int r0 = wr * 64 + (lane & 15);
    const int c0 = wc * 64 + (lane & 15);
    const int k8 = (lane >> 4) * 8;

    for (int kt = 0; kt < K; kt += 32) {
        async_copy16(gA + kt, ldsA);                          // rows 0..63
        async_copy16(gA + kt + (size_t)64 * K, ldsA + 2048);  // rows 64..127 (short offset 64*32)
        async_copy16(gB + kt, ldsB);
        async_copy16(gB + kt + (size_t)64 * K, ldsB + 2048);
        __syncthreads();                                      // compiler drains vmcnt before barrier
        short8 af[4], bfr[4];
        #pragma unroll
        for (int m = 0; m < 4; ++m) af[m] = *(const short8*)(As + (r0 + m * 16) * 32 + k8);
        #pragma unroll
        for (int n = 0; n < 4; ++n) bfr[n] = *(const short8*)(Bs + (c0 + n * 16) * 32 + k8);
        #pragma unroll
        for (int m = 0; m < 4; ++m)
            #pragma unroll
            for (int n = 0; n < 4; ++n)
                acc[m][n] = __builtin_amdgcn_mfma_f32_16x16x32_bf16(af[m], bfr[n], acc[m][n], 0, 0, 0);
        __syncthreads();
    }

    // C/D layout (HW-verified m89/m91): col=lane&15, row=(lane>>4)*4+i
    const int rowc = rowBase + wr * 64 + (lane >> 4) * 4;
    const int colc = colBase + wc * 64 + (lane & 15);
    #pragma unroll
    for (int n = 0; n < 4; ++n) {
        const float bz = bias[colc + n * 16];
        #pragma unroll
        for (int m = 0; m < 4; ++m)
            #pragma unroll
            for (int i = 0; i < 4; ++i) {
                const float v = acc[m][n][i] + bz;
                C[(size_t)(rowc + m * 16 + i) * 1024 + (colc + n * 16)] = f2bf(gelu_erf(v));
            }
    }
}

// ---------------- 5. masked softmax attention pooling, one block per (b, branch)
__global__ __launch_bounds__(256) void pool_kernel(const unsigned short* __restrict__ motion,
                                                   const unsigned short* __restrict__ appearance,
                                                   const int* __restrict__ lens,
                                                   const float* __restrict__ w_pool,
                                                   const float* __restrict__ b_pool,
                                                   float* __restrict__ out) {
    __shared__ float sm[256];
    __shared__ float red[8];
    const int b = blockIdx.x >> 1;
    const int which = blockIdx.x & 1;
    const unsigned short* mat;
    int Lm, valid;
    if (which == 0) { mat = motion + (size_t)b * 254 * 1024; Lm = 254; valid = lens[b] - 2; }
    else            { mat = appearance + (size_t)b * 256 * 1024; Lm = 256; valid = lens[b]; }
    const int t = threadIdx.x, lane = t & 63, wv = t >> 6;
    const float bp = b_pool[0];
    sm[t] = NEGF;
    __syncthreads();
    for (int l = wv; l < valid; l += 4) {        // wave per row
        const unsigned short* row = mat + (size_t)l * 1024;
        float sum = 0.f;
        #pragma unroll
        for (int j = 0; j < 4; ++j) {
            const int e = j * 256 + lane * 4;
            us4 hv = *(const us4*)(row + e);
            f32x4 w4 = *(const f32x4*)(w_pool + e);
            sum += bf2f(hv[0])*w4[0] + bf2f(hv[1])*w4[1] + bf2f(hv[2])*w4[2] + bf2f(hv[3])*w4[3];
        }
        #pragma unroll
        for (int off = 32; off; off >>= 1) sum += __shfl_xor(sum, off);
        if (lane == 0) sm[l] = gelu_erf(sum + bp);
    }
    __syncthreads();
    const float v = sm[t];
    float mx = v;
    #pragma unroll
    for (int off = 32; off; off >>= 1) mx = fmaxf(mx, __shfl_xor(mx, off));
    if (lane == 0) red[wv] = mx;
    __syncthreads();
    mx = fmaxf(fmaxf(red[0], red[1]), fmaxf(red[2], red[3]));
    const float e = expf(v - mx);                 // masked rows -> exactly 0
    float s = e;
    #pragma unroll
    for (int off = 32; off; off >>= 1) s += __shfl_xor(s, off);
    if (lane == 0) red[4 + wv] = s;
    __syncthreads();
    s = red[4] + red[5] + red[6] + red[7];
    sm[t] = e / s;
    __syncthreads();
    float acc0 = 0.f, acc1 = 0.f, acc2 = 0.f, acc3 = 0.f;
    for (int l = 0; l < Lm; ++l) {
        const float al = sm[l];                   // uniform -> scalar branch
        if (al > 0.f) {
            const unsigned short* row = mat + (size_t)l * 1024;
            acc0 += al * bf2f(row[t]);
            acc1 += al * bf2f(row[t + 256]);
            acc2 += al * bf2f(row[t + 512]);
            acc3 += al * bf2f(row[t + 768]);
        }
    }
    float* o = out + (size_t)b * 2048 + which * 1024;
    o[t] = acc0; o[t + 256] = acc1; o[t + 512] = acc2; o[t + 768] = acc3;
}

extern "C" void kernel_launch(void* const* d_in, const int* in_sizes, int n_in,
                              void* d_out, int out_size, void* d_ws, size_t ws_size,
                              hipStream_t stream) {
    const float* clip_ft   = (const float*)d_in[0];
    const int*   clip_lens = (const int*)d_in[1];
    const float* w_mot_wei = (const float*)d_in[2];
    const float* b_mot_wei = (const float*)d_in[3];
    const float* w_mot_fc  = (const float*)d_in[4];
    const float* b_mot_fc  = (const float*)d_in[5];
    const float* w_app_fc  = (const float*)d_in[6];
    const float* b_app_fc  = (const float*)d_in[7];
    const float* w_pool    = (const float*)d_in[8];
    const float* b_pool    = (const float*)d_in[9];
    float* out = (float*)d_out;

    char* ws = (char*)d_ws;
    size_t off = 0;
    auto carve = [&](size_t bytes) { void* p = ws + off; off += (bytes + 255) & ~(size_t)255; return p; };
    float*          scores = (float*)carve((size_t)16384 * 4);
    unsigned short* wmotT  = (unsigned short*)carve((size_t)1024 * 2048 * 2);
    unsigned short* wappT  = (unsigned short*)carve((size_t)1024 * 2048 * 2);
    unsigned short* appb   = (unsigned short*)carve((size_t)64 * 256 * 2048 * 2);
    unsigned short* vidb   = (unsigned short*)carve((size_t)64 * 254 * 2048 * 2);
    unsigned short* motion = (unsigned short*)carve((size_t)64 * 254 * 1024 * 2);
    unsigned short* appear = (unsigned short*)carve((size_t)64 * 256 * 1024 * 2);
    (void)ws_size; (void)in_sizes; (void)n_in; (void)out_size;

    wtrans_kernel<<<1024, 256, 0, stream>>>(w_mot_fc, wmotT);
    wtrans_kernel<<<1024, 256, 0, stream>>>(w_app_fc, wappT);
    score_kernel<<<4096, 256, 0, stream>>>(clip_ft, clip_lens, w_mot_wei, b_mot_wei, scores);
    prep_kernel<<<512, 256, 0, stream>>>(clip_ft, scores, appb, vidb);
    gemm_gelu_kernel<<<1016, 256, 0, stream>>>(vidb, wmotT, b_mot_fc, motion);   // M=16256
    gemm_gelu_kernel<<<1024, 256, 0, stream>>>(appb, wappT, b_app_fc, appear);   // M=16384
    pool_kernel<<<128, 256, 0, stream>>>(motion, appear, clip_lens, w_pool, b_pool, out);
}

// Round 3
// 362.157 us; speedup vs baseline: 1.1712x; 1.1712x over previous
//
#include <hip/hip_runtime.h>
#include <cstdint>

#define NEGF (-1e18f)
#define GK 2048   // GEMM K
#define GN 1024   // GEMM N

typedef __attribute__((ext_vector_type(8))) short short8;     // 8 bf16 (4 VGPRs) MFMA A/B frag
typedef __attribute__((ext_vector_type(4))) float f32x4;      // MFMA C/D frag
typedef __attribute__((ext_vector_type(4))) unsigned short us4;
typedef __attribute__((ext_vector_type(8))) unsigned short us8;

__device__ __forceinline__ unsigned short f2bf(float f) {
    unsigned int u = __float_as_uint(f);
    u += 0x7FFFu + ((u >> 16) & 1u);          // RNE
    return (unsigned short)(u >> 16);
}
__device__ __forceinline__ float bf2f(unsigned short h) {
    return __uint_as_float(((unsigned int)h) << 16);
}
__device__ __forceinline__ float gelu_erf(float x) {
    return 0.5f * x * (1.0f + erff(x * 0.70710678118654752f));
}
__device__ __forceinline__ void async_copy16(const void* g, void* l) {
    __builtin_amdgcn_global_load_lds(
        (const __attribute__((address_space(1))) unsigned int*)g,
        (__attribute__((address_space(3))) unsigned int*)l,
        16, 0, 0);
}

// ---------------- 1. weight transpose + bf16 convert: w[K=2048][N=1024] -> wT[N][K] bf16
__global__ __launch_bounds__(256) void wtrans_kernel(const float* __restrict__ w,
                                                     unsigned short* __restrict__ wT) {
    const int idx = blockIdx.x * 256 + threadIdx.x;   // 1024 blocks * 256
    const int n = idx & 1023;
    const int k0 = (idx >> 10) << 3;
    us8 o;
    #pragma unroll
    for (int j = 0; j < 8; ++j) o[j] = f2bf(w[(size_t)(k0 + j) * 1024 + n]);
    *(us8*)(wT + (size_t)n * 2048 + k0) = o;
}

// ---------------- 2. masked motion scores: (B*L) row-dots over D=2048
__global__ __launch_bounds__(256) void score_kernel(const float* __restrict__ clip_ft,
                                                    const int* __restrict__ lens,
                                                    const float* __restrict__ w,
                                                    const float* __restrict__ bsc,
                                                    float* __restrict__ scores) {
    const int r = blockIdx.x * 4 + (threadIdx.x >> 6);   // one wave per row
    const int lane = threadIdx.x & 63;
    const float* row = clip_ft + (size_t)r * 2048;
    float sum = 0.f;
    #pragma unroll
    for (int j = 0; j < 8; ++j) {
        const int k = (j * 64 + lane) * 4;
        f32x4 x = *(const f32x4*)(row + k);
        f32x4 ww = *(const f32x4*)(w + k);
        sum += x[0]*ww[0] + x[1]*ww[1] + x[2]*ww[2] + x[3]*ww[3];
    }
    #pragma unroll
    for (int off = 32; off; off >>= 1) sum += __shfl_xor(sum, off);
    if (lane == 0) {
        const int b = r >> 8, l = r & 255;
        float v = sum + bsc[0];
        if (l >= lens[b]) v = NEGF;
        scores[r] = v;
    }
}

// ---------------- 3. fused: app bf16 convert + window softmax + vid_clip bf16
// vid padded to [B][256][2048]: rows 254,255 per batch are zeros (GEMM-tile padding)
__global__ __launch_bounds__(256) void prep_kernel(const float* __restrict__ clip_ft,
                                                   const float* __restrict__ scores,
                                                   unsigned short* __restrict__ app,   // [B][256][2048]
                                                   unsigned short* __restrict__ vid) { // [B][256][2048]
    const int b = blockIdx.x >> 3;
    const int c = blockIdx.x & 7;
    const int t = threadIdx.x;
    const int d0 = t * 8;
    const int l0 = c * 32;
    const float* base = clip_ft + ((size_t)b * 256) * 2048 + d0;
    const float* sc = scores + b * 256;
    float x0[8], x1[8], cur[8];
    for (int i = 0; i < 34; ++i) {
        const int l = l0 + i;
        if (l < 256) {
            const f32x4* p = (const f32x4*)(base + (size_t)l * 2048);
            f32x4 u = p[0], v = p[1];
            #pragma unroll
            for (int j = 0; j < 4; ++j) { cur[j] = u[j]; cur[4 + j] = v[j]; }
            if (i < 32) {
                us8 o;
                #pragma unroll
                for (int j = 0; j < 8; ++j) o[j] = f2bf(cur[j]);
                *(us8*)(app + ((size_t)b * 256 + l) * 2048 + d0) = o;
            }
        }
        if (i >= 2) {
            const int lw = l - 2;
            if (lw < 254) {
                const float s0 = sc[lw], s1 = sc[lw + 1], s2 = sc[lw + 2];
                const float mx = fmaxf(s0, fmaxf(s1, s2));
                const float e0 = expf(s0 - mx), e1 = expf(s1 - mx), e2 = expf(s2 - mx);
                const float inv = 1.0f / (e0 + e1 + e2);
                const float a0 = e0 * inv, a1 = e1 * inv, a2 = e2 * inv;
                us8 o;
                #pragma unroll
                for (int j = 0; j < 8; ++j) o[j] = f2bf(a0 * x0[j] + a1 * x1[j] + a2 * cur[j]);
                *(us8*)(vid + ((size_t)b * 256 + lw) * 2048 + d0) = o;
            } else if (lw < 256) {
                us8 z = {};                                   // zero pad rows 254,255
                *(us8*)(vid + ((size_t)b * 256 + lw) * 2048 + d0) = z;
            }
        }
        #pragma unroll
        for (int j = 0; j < 8; ++j) { x0[j] = x1[j]; x1[j] = cur[j]; }
    }
}

// ---------------- 4. bf16 MFMA GEMM, 8-phase counted-vmcnt schedule (T2+T3+T4+T5)
// 256x256 tile, BK=64, 8 waves (2M x 4N), 128KB dbuf LDS, XOR slot-swizzle both-sides.
// A [16384][2048] bf16, Bt [1024][2048] bf16 (N-major), C [16384][1024] bf16, gelu+bias epilogue.
__global__ __launch_bounds__(512, 2) void gemm8_kernel(const unsigned short* __restrict__ A,
                                                       const unsigned short* __restrict__ Bt,
                                                       const float* __restrict__ bias,
                                                       unsigned short* __restrict__ C) {
    __shared__ __align__(16) unsigned short lds_[65536];      // 128 KB: [buf][A 32KB | B 32KB]
    const int t512 = threadIdx.x;
    const int lane = t512 & 63;
    const int wave = t512 >> 6;
    const int wm = wave >> 2;             // 0..1  (M split)
    const int wn = wave & 3;              // 0..3  (N split)
    const int lr = lane & 15;
    const int lk = lane >> 4;
    const int row0 = (blockIdx.x >> 2) * 256;
    const int col0 = (blockIdx.x & 3) * 256;

    // staging map: thread q stages 16B; LDS linear pos q*16B within chunk; source slot pre-swizzled
    const int srow = t512 >> 3;                         // 0..63 row within 64-row chunk
    const int sslot = (t512 & 7) ^ (srow & 7);          // inverse-swizzled global k-slot
    const unsigned short* gA = A + (size_t)(row0 + srow) * GK + sslot * 8;
    const unsigned short* gB = Bt + (size_t)(col0 + srow) * GK + sslot * 8;
    const int wbase = wave << 9;                        // wave-uniform LDS base (1KB/wave)

    f32x4 acc[8][4] = {};

#define STAGE_A(d, c, kt) async_copy16(gA + (size_t)((c) * 64) * GK + (kt) * 64, \
                                       lds_ + (d) * 32768 + (c) * 4096 + wbase)
#define STAGE_B(d, c, kt) async_copy16(gB + (size_t)((c) * 64) * GK + (kt) * 64, \
                                       lds_ + (d) * 32768 + 16384 + (c) * 4096 + wbase)
    // swizzled LDS reads (row stride 128B, 8 x 16B slots, slot ^= row&7)
#define RD_A(d, rt, ks) (*(const short8*)(lds_ + (d) * 32768 + (rt) * 64 + (((lk + ((ks) << 2)) ^ ((rt) & 7)) << 3)))
#define RD_B(d, nt, ks) (*(const short8*)(lds_ + (d) * 32768 + 16384 + (nt) * 64 + (((lk + ((ks) << 2)) ^ ((nt) & 7)) << 3)))

    // prologue: stage K-tile 0, order [A0,A2,B0,B1,B2,B3,A1,A3]; pos 0-5 needed at first P1
    STAGE_A(0, 0, 0); STAGE_A(0, 2, 0);
    STAGE_B(0, 0, 0); STAGE_B(0, 1, 0); STAGE_B(0, 2, 0); STAGE_B(0, 3, 0);
    STAGE_A(0, 1, 0); STAGE_A(0, 3, 0);
    asm volatile("s_waitcnt vmcnt(2)" ::: "memory");
    __builtin_amdgcn_s_barrier();

    short8 aF[4][2], bL[2][2], bH[2][2];
    const int arow = wm * 128;
    const int brow = wn * 64;

    for (int t = 0; t < 32; ++t) {
        const int d = t & 1, dn = d ^ 1;
        const int tn = (t + 1) & 31;      // wrapped prefetch keeps vmcnt arithmetic constant
        // ---- P1: read a[0-3],b[0-1]; stage A0,A2; MFMA Q00
        #pragma unroll
        for (int m = 0; m < 4; ++m) {
            aF[m][0] = RD_A(d, arow + m * 16 + lr, 0);
            aF[m][1] = RD_A(d, arow + m * 16 + lr, 1);
        }
        #pragma unroll
        for (int n = 0; n < 2; ++n) {
            bL[n][0] = RD_B(d, brow + n * 16 + lr, 0);
            bL[n][1] = RD_B(d, brow + n * 16 + lr, 1);
        }
        STAGE_A(dn, 0, tn); STAGE_A(dn, 2, tn);
        __builtin_amdgcn_s_barrier();
        __builtin_amdgcn_s_setprio(1);
        #pragma unroll
        for (int m = 0; m < 4; ++m)
            #pragma unroll
            for (int n = 0; n < 2; ++n)
                #pragma unroll
                for (int ks = 0; ks < 2; ++ks)
                    acc[m][n] = __builtin_amdgcn_mfma_f32_16x16x32_bf16(aF[m][ks], bL[n][ks], acc[m][n], 0, 0, 0);
        __builtin_amdgcn_s_setprio(0);
        __builtin_amdgcn_s_barrier();
        // ---- P2: read b[2-3]; stage B0,B1; MFMA Q01; vmcnt(4) releases prev A1,A3 for P3
        #pragma unroll
        for (int n = 0; n < 2; ++n) {
            bH[n][0] = RD_B(d, brow + 32 + n * 16 + lr, 0);
            bH[n][1] = RD_B(d, brow + 32 + n * 16 + lr, 1);
        }
        STAGE_B(dn, 0, tn); STAGE_B(dn, 1, tn);
        __builtin_amdgcn_s_barrier();
        __builtin_amdgcn_s_setprio(1);
        #pragma unroll
        for (int m = 0; m < 4; ++m)
            #pragma unroll
            for (int n = 0; n < 2; ++n)
                #pragma unroll
                for (int ks = 0; ks < 2; ++ks)
                    acc[m][2 + n] = __builtin_amdgcn_mfma_f32_16x16x32_bf16(aF[m][ks], bH[n][ks], acc[m][2 + n], 0, 0, 0);
        __builtin_amdgcn_s_setprio(0);
        asm volatile("s_waitcnt vmcnt(4)" ::: "memory");
        __builtin_amdgcn_s_barrier();
        // ---- P3: read a[4-7]; stage B2,B3; MFMA Q10
        #pragma unroll
        for (int m = 0; m < 4; ++m) {
            aF[m][0] = RD_A(d, arow + 64 + m * 16 + lr, 0);
            aF[m][1] = RD_A(d, arow + 64 + m * 16 + lr, 1);
        }
        STAGE_B(dn, 2, tn); STAGE_B(dn, 3, tn);
        __builtin_amdgcn_s_barrier();
        __builtin_amdgcn_s_setprio(1);
        #pragma unroll
        for (int m = 0; m < 4; ++m)
            #pragma unroll
            for (int n = 0; n < 2; ++n)
                #pragma unroll
                for (int ks = 0; ks < 2; ++ks)
                    acc[4 + m][n] = __builtin_amdgcn_mfma_f32_16x16x32_bf16(aF[m][ks], bL[n][ks], acc[4 + m][n], 0, 0, 0);
        __builtin_amdgcn_s_setprio(0);
        __builtin_amdgcn_s_barrier();
        // ---- P4: stage A1,A3; MFMA Q11; vmcnt(2) releases pos 0-5 for next P1
        STAGE_A(dn, 1, tn); STAGE_A(dn, 3, tn);
        __builtin_amdgcn_s_barrier();
        __builtin_amdgcn_s_setprio(1);
        #pragma unroll
        for (int m = 0; m < 4; ++m)
            #pragma unroll
            for (int n = 0; n < 2; ++n)
                #pragma unroll
                for (int ks = 0; ks < 2; ++ks)
                    acc[4 + m][2 + n] = __builtin_amdgcn_mfma_f32_16x16x32_bf16(aF[m][ks], bH[n][ks], acc[4 + m][2 + n], 0, 0, 0);
        __builtin_amdgcn_s_setprio(0);
        asm volatile("s_waitcnt vmcnt(2)" ::: "memory");
        __builtin_amdgcn_s_barrier();
    }
#undef STAGE_A
#undef STAGE_B
#undef RD_A
#undef RD_B

    // epilogue: C/D layout col=lane&15, row=(lane>>4)*4+i (HW-verified m89/m91)
    #pragma unroll
    for (int n = 0; n < 4; ++n) {
        const int col = col0 + wn * 64 + n * 16 + lr;
        const float bz = bias[col];
        #pragma unroll
        for (int m = 0; m < 8; ++m) {
            const int row = row0 + wm * 128 + m * 16 + lk * 4;
            #pragma unroll
            for (int i = 0; i < 4; ++i) {
                const float v = acc[m][n][i] + bz;
                C[(size_t)(row + i) * GN + col] = f2bf(gelu_erf(v));
            }
        }
    }
}

// ---------------- 5. masked softmax attention pooling, one block per (b, branch)
__global__ __launch_bounds__(256) void pool_kernel(const unsigned short* __restrict__ motion,
                                                   const unsigned short* __restrict__ appearance,
                                                   const int* __restrict__ lens,
                                                   const float* __restrict__ w_pool,
                                                   const float* __restrict__ b_pool,
                                                   float* __restrict__ out) {
    __shared__ float sm[256];
    __shared__ float red[8];
    const int b = blockIdx.x >> 1;
    const int which = blockIdx.x & 1;
    const unsigned short* mat;
    int Lm, valid;
    if (which == 0) { mat = motion + (size_t)b * 256 * 1024; Lm = 254; valid = lens[b] - 2; }
    else            { mat = appearance + (size_t)b * 256 * 1024; Lm = 256; valid = lens[b]; }
    const int t = threadIdx.x, lane = t & 63, wv = t >> 6;
    const float bp = b_pool[0];
    sm[t] = NEGF;
    __syncthreads();
    for (int l = wv; l < valid; l += 4) {        // wave per row
        const unsigned short* row = mat + (size_t)l * 1024;
        float sum = 0.f;
        #pragma unroll
        for (int j = 0; j < 4; ++j) {
            const int e = j * 256 + lane * 4;
            us4 hv = *(const us4*)(row + e);
            f32x4 w4 = *(const f32x4*)(w_pool + e);
            sum += bf2f(hv[0])*w4[0] + bf2f(hv[1])*w4[1] + bf2f(hv[2])*w4[2] + bf2f(hv[3])*w4[3];
        }
        #pragma unroll
        for (int off = 32; off; off >>= 1) sum += __shfl_xor(sum, off);
        if (lane == 0) sm[l] = gelu_erf(sum + bp);
    }
    __syncthreads();
    const float v = sm[t];
    float mx = v;
    #pragma unroll
    for (int off = 32; off; off >>= 1) mx = fmaxf(mx, __shfl_xor(mx, off));
    if (lane == 0) red[wv] = mx;
    __syncthreads();
    mx = fmaxf(fmaxf(red[0], red[1]), fmaxf(red[2], red[3]));
    const float e = expf(v - mx);                 // masked rows -> exactly 0
    float s = e;
    #pragma unroll
    for (int off = 32; off; off >>= 1) s += __shfl_xor(s, off);
    if (lane == 0) red[4 + wv] = s;
    __syncthreads();
    s = red[4] + red[5] + red[6] + red[7];
    sm[t] = e / s;
    __syncthreads();
    float acc0 = 0.f, acc1 = 0.f, acc2 = 0.f, acc3 = 0.f;
    for (int l = 0; l < Lm; ++l) {
        const float al = sm[l];                   // uniform -> scalar branch
        if (al > 0.f) {
            const unsigned short* row = mat + (size_t)l * 1024;
            acc0 += al * bf2f(row[t]);
            acc1 += al * bf2f(row[t + 256]);
            acc2 += al * bf2f(row[t + 512]);
            acc3 += al * bf2f(row[t + 768]);
        }
    }
    float* o = out + (size_t)b * 2048 + which * 1024;
    o[t] = acc0; o[t + 256] = acc1; o[t + 512] = acc2; o[t + 768] = acc3;
}

extern "C" void kernel_launch(void* const* d_in, const int* in_sizes, int n_in,
                              void* d_out, int out_size, void* d_ws, size_t ws_size,
                              hipStream_t stream) {
    const float* clip_ft   = (const float*)d_in[0];
    const int*   clip_lens = (const int*)d_in[1];
    const float* w_mot_wei = (const float*)d_in[2];
    const float* b_mot_wei = (const float*)d_in[3];
    const float* w_mot_fc  = (const float*)d_in[4];
    const float* b_mot_fc  = (const float*)d_in[5];
    const float* w_app_fc  = (const float*)d_in[6];
    const float* b_app_fc  = (const float*)d_in[7];
    const float* w_pool    = (const float*)d_in[8];
    const float* b_pool    = (const float*)d_in[9];
    float* out = (float*)d_out;

    char* ws = (char*)d_ws;
    size_t off = 0;
    auto carve = [&](size_t bytes) { void* p = ws + off; off += (bytes + 255) & ~(size_t)255; return p; };
    float*          scores = (float*)carve((size_t)16384 * 4);
    unsigned short* wmotT  = (unsigned short*)carve((size_t)1024 * 2048 * 2);
    unsigned short* wappT  = (unsigned short*)carve((size_t)1024 * 2048 * 2);
    unsigned short* appb   = (unsigned short*)carve((size_t)64 * 256 * 2048 * 2);
    unsigned short* vidb   = (unsigned short*)carve((size_t)64 * 256 * 2048 * 2);  // padded rows
    unsigned short* motion = (unsigned short*)carve((size_t)64 * 256 * 1024 * 2);  // padded rows
    unsigned short* appear = (unsigned short*)carve((size_t)64 * 256 * 1024 * 2);
    (void)ws_size; (void)in_sizes; (void)n_in; (void)out_size;

    wtrans_kernel<<<1024, 256, 0, stream>>>(w_mot_fc, wmotT);
    wtrans_kernel<<<1024, 256, 0, stream>>>(w_app_fc, wappT);
    score_kernel<<<4096, 256, 0, stream>>>(clip_ft, clip_lens, w_mot_wei, b_mot_wei, scores);
    prep_kernel<<<512, 256, 0, stream>>>(clip_ft, scores, appb, vidb);
    gemm8_kernel<<<256, 512, 0, stream>>>(vidb, wmotT, b_mot_fc, motion);   // M=16384 (padded)
    gemm8_kernel<<<256, 512, 0, stream>>>(appb, wappT, b_app_fc, appear);   // M=16384
    pool_kernel<<<128, 256, 0, stream>>>(motion, appear, clip_lens, w_pool, b_pool, out);
}